// Round 9
// baseline (519.392 us; speedup 1.0000x reference)
//
#include <hip/hip_runtime.h>
#include <hip/hip_bf16.h>
#include <math.h>

// Problem constants
#define BB 32
#define TT 2048
#define DD 64
#define NCHUNK 4
#define TCH (TT / NCHUNK)               // 512 targets per block
#define NBLK (BB * (TT / 256) * NCHUNK) // 1024 k_main blocks
#define LOG2E 1.4426950408889634f
#define C2    0.7213475204444817f       // log2(e)/2
#define LN2   0.6931471805599453f

typedef __attribute__((ext_vector_type(8))) _Float16 h16x8;  // 8 f16 (4 VGPRs)
typedef __attribute__((ext_vector_type(4))) float    f32x4;  // MFMA C/D frag
typedef __attribute__((ext_vector_type(2))) float    f32x2;  // packed-math pair

// ws layout (bytes)
#define OFF_M    0u            // float[32*64]   = 8 KB
#define OFF_CNT  8192u         // int counter (+pad to 256)
#define OFF_TICN 8448u         // float[65536]   = 256 KB
#define OFF_HI   270592u       // f16[32*2048*64] = 8 MB
#define OFF_LO   8659200u      // f16[...]        = 8 MB
#define OFF_PART 17047808u     // float2[4*65536] = 2 MB   (end ~19.1 MB)

__device__ __forceinline__ float h2f(unsigned short u) {
    _Float16 h; __builtin_memcpy(&h, &u, 2); return (float)h;
}
__device__ __forceinline__ unsigned short f2h(float f) {
    _Float16 h = (_Float16)f; unsigned short u; __builtin_memcpy(&u, &h, 2); return u;
}
__device__ __forceinline__ float fexp2(float x) {
    float r; asm("v_exp_f32 %0, %1" : "=v"(r) : "v"(x)); return r;
}
__device__ __forceinline__ float flog2(float x) {
    float r; asm("v_log_f32 %0, %1" : "=v"(r) : "v"(x)); return r;
}
// async global->LDS, 16B per lane; LDS dest = wave-uniform base + lane*16
__device__ __forceinline__ void gload16(const unsigned short* g, unsigned short* s) {
    __builtin_amdgcn_global_load_lds(
        (const __attribute__((address_space(1))) unsigned int*)g,
        (__attribute__((address_space(3))) unsigned int*)s, 16, 0, 0);
}

// ---------- kernel 1: fused {L2-normalize -> f16 hi/lo + M sum} and tic-normalize ----------
// blocks [0, BB*16): embedding prep; blocks [BB*16, BB*16+BB): tic rows.
__global__ void k_prep(const float* __restrict__ emb, const float* __restrict__ tic,
                       unsigned short* __restrict__ hi, unsigned short* __restrict__ lo,
                       float* __restrict__ M, float* __restrict__ ticn) {
    if (blockIdx.x >= BB * 16) {
        int b = blockIdx.x - BB * 16;
        const float* row = tic + b * TT;
        float m = -1e30f;
        for (int t = threadIdx.x; t < TT; t += 256) m = fmaxf(m, row[t]);
        #pragma unroll
        for (int off = 32; off; off >>= 1) m = fmaxf(m, __shfl_xor(m, off));
        __shared__ float red[4];
        if ((threadIdx.x & 63) == 0) red[threadIdx.x >> 6] = m;
        __syncthreads();
        float mm = fmaxf(fmaxf(red[0], red[1]), fmaxf(red[2], red[3]));
        float inv = 1.0f / mm;
        for (int t = threadIdx.x; t < TT; t += 256) ticn[b * TT + t] = row[t] * inv;
        return;
    }
    const int b   = blockIdx.x >> 4;
    const int R0  = (blockIdx.x & 15) * 128;
    const int w   = threadIdx.x >> 6;
    const int l   = threadIdx.x & 63;
    const int sub = l >> 4;
    const int d4  = l & 15;

    float macc[4] = {0.f, 0.f, 0.f, 0.f};
    #pragma unroll
    for (int it = 0; it < 8; ++it) {
        int row = R0 + w * 32 + it * 4 + sub;
        size_t base = ((size_t)(b * TT + row)) * DD + d4 * 4;
        float4 v = *(const float4*)(emb + base);
        float ss = v.x * v.x + v.y * v.y + v.z * v.z + v.w * v.w;
        #pragma unroll
        for (int off = 1; off < 16; off <<= 1) ss += __shfl_xor(ss, off);
        float inv = 1.0f / fmaxf(sqrtf(ss), 1e-8f);
        float n0 = v.x * inv, n1 = v.y * inv, n2 = v.z * inv, n3 = v.w * inv;
        ushort4 hv, lv;
        hv.x = f2h(n0); lv.x = f2h(n0 - h2f(hv.x));
        hv.y = f2h(n1); lv.y = f2h(n1 - h2f(hv.y));
        hv.z = f2h(n2); lv.z = f2h(n2 - h2f(hv.z));
        hv.w = f2h(n3); lv.w = f2h(n3 - h2f(hv.w));
        *(ushort4*)(hi + base) = hv;
        *(ushort4*)(lo + base) = lv;
        macc[0] += n0; macc[1] += n1; macc[2] += n2; macc[3] += n3;
    }
    #pragma unroll
    for (int j = 0; j < 4; ++j) {
        macc[j] += __shfl_xor(macc[j], 16);
        macc[j] += __shfl_xor(macc[j], 32);
    }
    if (l < 16) {
        #pragma unroll
        for (int j = 0; j < 4; ++j)
            atomicAdd(&M[b * DD + d4 * 4 + j], macc[j]);
    }
}

// ---------- kernel 2: MFMA GEMM + packed KL epilogue + last-block finish ----------
// grid ((TT/256)*NCHUNK=32, BB=32), 512 thr = 8 waves; wave owns 32 p-rows.
// Double-buffered B-tile via global_load_lds (pre-swizzled source), ONE barrier/tile.
__launch_bounds__(512, 4)
__global__ void k_main(const unsigned short* __restrict__ hi,
                       const unsigned short* __restrict__ lo,
                       const float* __restrict__ ticn,
                       const float* __restrict__ M,
                       float2* __restrict__ part,
                       int* __restrict__ cnt,
                       float* __restrict__ out) {
    __shared__ unsigned short Bh[2][64 * 64];   // 2 x 8 KB, swizzled [t][d]
    __shared__ float redf[8];
    __shared__ int lastFlag;

    const int b     = blockIdx.y;
    const int px    = blockIdx.x >> 2;
    const int chunk = blockIdx.x & 3;
    const int p0    = px * 256;
    const int tbase = chunk * TCH;
    const int tid   = threadIdx.x;
    const int w     = tid >> 6;
    const int l     = tid & 63;
    const int lr    = l & 15;
    const int lg    = l >> 4;

    // staging map: wave w stages rows [w*8, w*8+8); lane l -> row w*8+(l>>3),
    // slot chunk l&7; SOURCE chunk pre-swizzled = (l&7) ^ (l>>3) (since row&7 == l>>3)
    const size_t lane_src = (size_t)(w * 8 + (l >> 3)) * DD + (((l & 7) ^ (l >> 3)) << 3);
    unsigned short* sdst = &Bh[0][w * 8 * 64];   // buffer 1 = +4096 ushorts
    const unsigned short* hb = hi + (size_t)(b * TT) * DD;

    // --- persistent A fragments: rows p0 + w*32 + mi*16 + lr, k = ks*32 + lg*8 ---
    h16x8 Ah[2][2], Al[2][2];
    #pragma unroll
    for (int mi = 0; mi < 2; ++mi)
        #pragma unroll
        for (int ks = 0; ks < 2; ++ks) {
            size_t off = ((size_t)(b * TT + p0 + w * 32 + mi * 16 + lr)) * DD + ks * 32 + lg * 8;
            Ah[mi][ks] = *(const h16x8*)(hi + off);
            Al[mi][ks] = *(const h16x8*)(lo + off);
        }

    // --- sinv: dot(ne_p, M) from A-frags ---
    const float* Mb = M + b * DD;
    float mv[16];
    *(float4*)&mv[0]  = *(const float4*)(Mb + lg * 8);
    *(float4*)&mv[4]  = *(const float4*)(Mb + lg * 8 + 4);
    *(float4*)&mv[8]  = *(const float4*)(Mb + 32 + lg * 8);
    *(float4*)&mv[12] = *(const float4*)(Mb + 32 + lg * 8 + 4);
    float dotv[2], tpl[2];
    #pragma unroll
    for (int mi = 0; mi < 2; ++mi) {
        float s = 0.f;
        #pragma unroll
        for (int ks = 0; ks < 2; ++ks)
            #pragma unroll
            for (int e = 0; e < 8; ++e) {
                float av = (float)Ah[mi][ks][e] + (float)Al[mi][ks][e];
                s = fmaf(av, mv[ks * 8 + e], s);
            }
        s += __shfl_xor(s, 16);
        s += __shfl_xor(s, 32);
        dotv[mi] = s;                                   // dot of row mi*16+lr
        tpl[mi]  = ticn[b * TT + p0 + w * 32 + mi * 16 + lr];
    }

    // --- per-row packed constants; C rows this lane owns: mi*16 + lg*4 + pr*2 + j ---
    f32x2 a2[2][2], b2[2][2], si2[2][2], sip2[2][2], SP2[2][2], KA2[2][2];
    #pragma unroll
    for (int mi = 0; mi < 2; ++mi)
        #pragma unroll
        for (int pr = 0; pr < 2; ++pr)
            #pragma unroll
            for (int j = 0; j < 2; ++j) {
                int rsel = lg * 4 + pr * 2 + j;
                float dv = __shfl(dotv[mi], rsel);
                float tp = __shfl(tpl[mi], rsel);
                float si = 1.0f / (dv + (float)TT);
                a2[mi][pr][j]   = -C2 * tp * tp;
                b2[mi][pr][j]   = LOG2E * tp;
                si2[mi][pr][j]  = si;
                sip2[mi][pr][j] = si + 1e-6f;
                SP2[mi][pr][j]  = 0.f;
                KA2[mi][pr][j]  = 0.f;
            }

    // --- precomputed swizzled B-frag LDS offsets (ushort units) ---
    int offU[4][2];
    #pragma unroll
    for (int ni = 0; ni < 4; ++ni)
        #pragma unroll
        for (int ks = 0; ks < 2; ++ks) {
            int rB = ni * 16 + lr, kc = ks * 4 + lg;
            offU[ni][ks] = rB * 64 + ((kc ^ (rB & 7)) << 3);
        }

    // --- t-loop: double-buffered stage, one barrier per tile ---
    gload16(hb + (size_t)tbase * DD + lane_src, sdst);   // prologue: tile 0 -> buf 0
    __syncthreads();

    #pragma unroll 2
    for (int tile = 0; tile < TCH / 64; ++tile) {
        const int cur = tile & 1;
        const int t0  = tbase + tile * 64;
        if (tile + 1 < TCH / 64)                          // stage next tile early
            gload16(hb + (size_t)(t0 + 64) * DD + lane_src, sdst + (cur ^ 1) * 4096);

        h16x8 Fh[4][2];
        #pragma unroll
        for (int ni = 0; ni < 4; ++ni)
            #pragma unroll
            for (int ks = 0; ks < 2; ++ks)
                Fh[ni][ks] = *(const h16x8*)&Bh[cur][offU[ni][ks]];

        float tt[4], qq[4];
        #pragma unroll
        for (int ni = 0; ni < 4; ++ni) {
            tt[ni] = ticn[b * TT + t0 + ni * 16 + lr];
            qq[ni] = (-C2 * tt[ni]) * tt[ni];
        }

        f32x4 acc[2][4];
        #pragma unroll
        for (int mi = 0; mi < 2; ++mi)
            #pragma unroll
            for (int ni = 0; ni < 4; ++ni) {
                f32x4 a = {0.f, 0.f, 0.f, 0.f};
                a = __builtin_amdgcn_mfma_f32_16x16x32_f16(Ah[mi][0], Fh[ni][0], a, 0, 0, 0);
                a = __builtin_amdgcn_mfma_f32_16x16x32_f16(Ah[mi][1], Fh[ni][1], a, 0, 0, 0);
                a = __builtin_amdgcn_mfma_f32_16x16x32_f16(Al[mi][0], Fh[ni][0], a, 0, 0, 0);
                a = __builtin_amdgcn_mfma_f32_16x16x32_f16(Al[mi][1], Fh[ni][1], a, 0, 0, 0);
                acc[mi][ni] = a;
            }

        // packed KL epilogue
        #pragma unroll
        for (int mi = 0; mi < 2; ++mi)
            #pragma unroll
            for (int ni = 0; ni < 4; ++ni) {
                f32x2 tt2 = {tt[ni], tt[ni]};
                f32x2 qq2 = {qq[ni], qq[ni]};
                #pragma unroll
                for (int pr = 0; pr < 2; ++pr) {
                    f32x2 acc2 = {acc[mi][ni][2 * pr], acc[mi][ni][2 * pr + 1]};
                    f32x2 arg  = b2[mi][pr] * tt2 + a2[mi][pr];
                    arg        = arg + qq2;
                    f32x2 e    = {fexp2(arg[0]), fexp2(arg[1])};
                    f32x2 x    = acc2 * si2[mi][pr] + sip2[mi][pr];
                    f32x2 l2v  = {flog2(x[0]), flog2(x[1])};
                    f32x2 d    = arg - l2v;
                    KA2[mi][pr] = e * d + KA2[mi][pr];
                    SP2[mi][pr] = SP2[mi][pr] + e;
                }
            }

        __syncthreads();   // drains vmcnt (stage landed under compute) + lgkm; swap
    }

    // --- reduce over 16 col-lanes per lg group, write partials ---
    #pragma unroll
    for (int mi = 0; mi < 2; ++mi)
        #pragma unroll
        for (int pr = 0; pr < 2; ++pr)
            #pragma unroll
            for (int off = 1; off < 16; off <<= 1) {
                SP2[mi][pr][0] += __shfl_xor(SP2[mi][pr][0], off);
                SP2[mi][pr][1] += __shfl_xor(SP2[mi][pr][1], off);
                KA2[mi][pr][0] += __shfl_xor(KA2[mi][pr][0], off);
                KA2[mi][pr][1] += __shfl_xor(KA2[mi][pr][1], off);
            }
    if (lr == 0) {
        #pragma unroll
        for (int mi = 0; mi < 2; ++mi)
            #pragma unroll
            for (int pr = 0; pr < 2; ++pr)
                #pragma unroll
                for (int j = 0; j < 2; ++j) {
                    int p = p0 + w * 32 + mi * 16 + lg * 4 + pr * 2 + j;
                    part[(size_t)chunk * (BB * TT) + b * TT + p] =
                        make_float2(SP2[mi][pr][j], KA2[mi][pr][j]);
                }
    }

    // --- last block combines partials and writes the scalar ---
    __threadfence();                    // release partials device-wide
    if (tid == 0) {
        int old = atomicAdd(cnt, 1);
        lastFlag = (old == NBLK - 1);
    }
    __syncthreads();
    if (!lastFlag) return;
    __threadfence();                    // acquire side
    float tot = 0.f;
    for (int g = tid; g < BB * TT; g += 512) {
        float SP = 0.f, KA = 0.f;
        #pragma unroll
        for (int c = 0; c < NCHUNK; ++c) {
            float2 q = part[(size_t)c * (BB * TT) + g];
            SP += q.x; KA += q.y;
        }
        tot += LN2 * (KA / SP) - __logf(SP);
    }
    #pragma unroll
    for (int off = 32; off; off >>= 1) tot += __shfl_xor(tot, off);
    if (l == 0) redf[w] = tot;
    __syncthreads();
    if (tid == 0) {
        float s = 0.f;
        #pragma unroll
        for (int i = 0; i < 8; ++i) s += redf[i];
        out[0] = s * (1.0f / 65536.0f);   // / (B * P)
    }
}

extern "C" void kernel_launch(void* const* d_in, const int* in_sizes, int n_in,
                              void* d_out, int out_size, void* d_ws, size_t ws_size,
                              hipStream_t stream) {
    const float* emb = (const float*)d_in[0];  // [B, T, D] fp32
    const float* tic = (const float*)d_in[1];  // [B, T] fp32
    float* out = (float*)d_out;
    char*  ws  = (char*)d_ws;

    float*          M    = (float*)(ws + OFF_M);
    int*            cnt  = (int*)(ws + OFF_CNT);
    float*          ticn = (float*)(ws + OFF_TICN);
    unsigned short* hi   = (unsigned short*)(ws + OFF_HI);
    unsigned short* lo   = (unsigned short*)(ws + OFF_LO);
    float2*         part = (float2*)(ws + OFF_PART);

    hipMemsetAsync(ws + OFF_M, 0, OFF_TICN, stream);   // zero M + counter

    k_prep<<<BB * 16 + BB, 256, 0, stream>>>(emb, tic, hi, lo, M, ticn);
    k_main<<<dim3((TT / 256) * NCHUNK, BB), 512, 0, stream>>>(hi, lo, ticn, M, part, cnt, out);
}

// Round 10
// 391.589 us; speedup vs baseline: 1.3264x; 1.3264x over previous
//
#include <hip/hip_runtime.h>
#include <hip/hip_bf16.h>
#include <math.h>

// Problem constants
#define BB 32
#define TT 2048
#define DD 64
#define NCHUNK 4
#define TCH (TT / NCHUNK)               // 512 targets per block
#define NBLK ((TT / 256) * NCHUNK * BB) // 1024 k_main blocks
#define LOG2E 1.4426950408889634f
#define C2    0.7213475204444817f       // log2(e)/2
#define LN2   0.6931471805599453f

typedef __attribute__((ext_vector_type(8))) _Float16 h16x8;  // 8 f16 (4 VGPRs)
typedef __attribute__((ext_vector_type(4))) float    f32x4;  // MFMA C/D frag

// ws layout (bytes)
#define OFF_M    0u            // float[32*64]    = 8 KB
#define OFF_CNT  8192u         // int counter (pad to 256 B)
#define OFF_TICN 8448u         // float[65536]    = 256 KB
#define OFF_HI   270592u       // f16[32*2048*64] = 8 MB
#define OFF_LO   8659200u      // f16[...]        = 8 MB
#define OFF_PART 17047808u     // float2[4*65536] = 2 MB   (end ~19.1 MB)

__device__ __forceinline__ float h2f(unsigned short u) {
    _Float16 h; __builtin_memcpy(&h, &u, 2); return (float)h;
}
__device__ __forceinline__ unsigned short f2h(float f) {
    _Float16 h = (_Float16)f; unsigned short u; __builtin_memcpy(&u, &h, 2); return u;
}
__device__ __forceinline__ float fexp2(float x) {
    float r; asm("v_exp_f32 %0, %1" : "=v"(r) : "v"(x)); return r;
}
__device__ __forceinline__ float flog2(float x) {
    float r; asm("v_log_f32 %0, %1" : "=v"(r) : "v"(x)); return r;
}

// ---------- kernel 1: fused {L2-normalize -> f16 hi/lo + M sum} and tic-normalize ----------
// blocks [0, BB*16): embedding prep; blocks [BB*16, BB*16+BB): tic rows.
__global__ void k_prep(const float* __restrict__ emb, const float* __restrict__ tic,
                       unsigned short* __restrict__ hi, unsigned short* __restrict__ lo,
                       float* __restrict__ M, float* __restrict__ ticn) {
    if (blockIdx.x >= BB * 16) {
        int b = blockIdx.x - BB * 16;
        const float* row = tic + b * TT;
        float m = -1e30f;
        for (int t = threadIdx.x; t < TT; t += 256) m = fmaxf(m, row[t]);
        #pragma unroll
        for (int off = 32; off; off >>= 1) m = fmaxf(m, __shfl_xor(m, off));
        __shared__ float red[4];
        if ((threadIdx.x & 63) == 0) red[threadIdx.x >> 6] = m;
        __syncthreads();
        float mm = fmaxf(fmaxf(red[0], red[1]), fmaxf(red[2], red[3]));
        float inv = 1.0f / mm;
        for (int t = threadIdx.x; t < TT; t += 256) ticn[b * TT + t] = row[t] * inv;
        return;
    }
    const int b   = blockIdx.x >> 4;
    const int R0  = (blockIdx.x & 15) * 128;
    const int w   = threadIdx.x >> 6;
    const int l   = threadIdx.x & 63;
    const int sub = l >> 4;
    const int d4  = l & 15;

    float macc[4] = {0.f, 0.f, 0.f, 0.f};
    #pragma unroll
    for (int it = 0; it < 8; ++it) {
        int row = R0 + w * 32 + it * 4 + sub;
        size_t base = ((size_t)(b * TT + row)) * DD + d4 * 4;
        float4 v = *(const float4*)(emb + base);
        float ss = v.x * v.x + v.y * v.y + v.z * v.z + v.w * v.w;
        #pragma unroll
        for (int off = 1; off < 16; off <<= 1) ss += __shfl_xor(ss, off);
        float inv = 1.0f / fmaxf(sqrtf(ss), 1e-8f);
        float n0 = v.x * inv, n1 = v.y * inv, n2 = v.z * inv, n3 = v.w * inv;
        ushort4 hv, lv;
        hv.x = f2h(n0); lv.x = f2h(n0 - h2f(hv.x));
        hv.y = f2h(n1); lv.y = f2h(n1 - h2f(hv.y));
        hv.z = f2h(n2); lv.z = f2h(n2 - h2f(hv.z));
        hv.w = f2h(n3); lv.w = f2h(n3 - h2f(hv.w));
        *(ushort4*)(hi + base) = hv;
        *(ushort4*)(lo + base) = lv;
        macc[0] += n0; macc[1] += n1; macc[2] += n2; macc[3] += n3;
    }
    #pragma unroll
    for (int j = 0; j < 4; ++j) {
        macc[j] += __shfl_xor(macc[j], 16);
        macc[j] += __shfl_xor(macc[j], 32);
    }
    if (l < 16) {
        #pragma unroll
        for (int j = 0; j < 4; ++j)
            atomicAdd(&M[b * DD + d4 * 4 + j], macc[j]);
    }
}

// ---------- kernel 2: MFMA GEMM + fused KL epilogue (round-6 hot loop) ----------
// grid ((TT/256)*NCHUNK = 32, BB = 32), 512 thr = 8 waves; wave owns 32 p-rows.
// Reg-staged B-tile in XOR-swizzled LDS, 2 barriers/tile — measured 83 us, 0 conflicts.
__launch_bounds__(512, 4)
__global__ void k_main(const unsigned short* __restrict__ hi,
                       const unsigned short* __restrict__ lo,
                       const float* __restrict__ ticn,
                       const float* __restrict__ M,
                       float2* __restrict__ part,
                       int* __restrict__ cnt,
                       float* __restrict__ out) {
    __shared__ unsigned short Bh[64 * 64];   // 8 KB, swizzled [t][d]
    __shared__ float redf[8];
    __shared__ int lastFlag;

    const int b     = blockIdx.y;
    const int px    = blockIdx.x >> 2;
    const int chunk = blockIdx.x & 3;
    const int p0    = px * 256;
    const int tbase = chunk * TCH;
    const int tid   = threadIdx.x;
    const int w     = tid >> 6;
    const int l     = tid & 63;
    const int lr    = l & 15;
    const int lg    = l >> 4;

    // --- persistent A fragments: rows p0 + w*32 + mi*16 + lr, k = ks*32 + lg*8 ---
    h16x8 Ah[2][2], Al[2][2];
    #pragma unroll
    for (int mi = 0; mi < 2; ++mi)
        #pragma unroll
        for (int ks = 0; ks < 2; ++ks) {
            size_t off = ((size_t)(b * TT + p0 + w * 32 + mi * 16 + lr)) * DD + ks * 32 + lg * 8;
            Ah[mi][ks] = *(const h16x8*)(hi + off);
            Al[mi][ks] = *(const h16x8*)(lo + off);
        }

    // --- sinv: dot(ne_p, M) from A-frags (M direct from global, L2-hot) ---
    const float* Mb = M + b * DD;
    float mv[16];
    *(float4*)&mv[0]  = *(const float4*)(Mb + lg * 8);
    *(float4*)&mv[4]  = *(const float4*)(Mb + lg * 8 + 4);
    *(float4*)&mv[8]  = *(const float4*)(Mb + 32 + lg * 8);
    *(float4*)&mv[12] = *(const float4*)(Mb + 32 + lg * 8 + 4);
    float dotv[2], tpl[2];
    #pragma unroll
    for (int mi = 0; mi < 2; ++mi) {
        float s = 0.f;
        #pragma unroll
        for (int ks = 0; ks < 2; ++ks)
            #pragma unroll
            for (int e = 0; e < 8; ++e) {
                float av = (float)Ah[mi][ks][e] + (float)Al[mi][ks][e];
                s = fmaf(av, mv[ks * 8 + e], s);
            }
        s += __shfl_xor(s, 16);
        s += __shfl_xor(s, 32);
        dotv[mi] = s;                                   // dot of row mi*16+lr
        tpl[mi]  = ticn[b * TT + p0 + w * 32 + mi * 16 + lr];
    }

    // --- per-row constants (C rows mi*16 + lg*4 + rr) ---
    float a_[2][4], b_[2][4], si_[2][4], sip_[2][4], SP[2][4], KA[2][4];
    #pragma unroll
    for (int mi = 0; mi < 2; ++mi)
        #pragma unroll
        for (int rr = 0; rr < 4; ++rr) {
            float dv = __shfl(dotv[mi], lg * 4 + rr);
            float tp = __shfl(tpl[mi],  lg * 4 + rr);
            float si = 1.0f / (dv + (float)TT);
            si_[mi][rr]  = si;
            sip_[mi][rr] = si + 1e-6f;
            a_[mi][rr] = -C2 * tp * tp;
            b_[mi][rr] = LOG2E * tp;
            SP[mi][rr] = 0.f; KA[mi][rr] = 0.f;
        }

    // --- t-loop (round-6 structure, verbatim) ---
    for (int tile = 0; tile < TCH / 64; ++tile) {
        const int t0 = tbase + tile * 64;
        __syncthreads();
        {   // stage B-tile (64 t x 64 d, hi only), XOR-swizzled 16B chunks
            int r  = tid >> 3;
            int kc = tid & 7;
            size_t g = ((size_t)(b * TT + t0 + r)) * DD + kc * 8;
            int dst = r * 64 + ((kc ^ (r & 7)) << 3);
            *(ushort4*)&Bh[dst] = *(const ushort4*)(hi + g);
            *(ushort4*)&Bh[dst + 4] = *(const ushort4*)(hi + g + 4);
        }
        __syncthreads();

        // B fragments
        h16x8 Fh[4][2];
        #pragma unroll
        for (int ni = 0; ni < 4; ++ni) {
            int rB = ni * 16 + lr;
            #pragma unroll
            for (int ks = 0; ks < 2; ++ks) {
                int kc  = ks * 4 + lg;
                int off = rB * 64 + ((kc ^ (rB & 7)) << 3);
                Fh[ni][ks] = *(const h16x8*)&Bh[off];
            }
        }

        // MFMA: acc = hi_a.hi_b + lo_a.hi_b
        f32x4 acc[2][4];
        #pragma unroll
        for (int mi = 0; mi < 2; ++mi)
            #pragma unroll
            for (int ni = 0; ni < 4; ++ni) {
                f32x4 a = {0.f, 0.f, 0.f, 0.f};
                a = __builtin_amdgcn_mfma_f32_16x16x32_f16(Ah[mi][0], Fh[ni][0], a, 0, 0, 0);
                a = __builtin_amdgcn_mfma_f32_16x16x32_f16(Ah[mi][1], Fh[ni][1], a, 0, 0, 0);
                a = __builtin_amdgcn_mfma_f32_16x16x32_f16(Al[mi][0], Fh[ni][0], a, 0, 0, 0);
                a = __builtin_amdgcn_mfma_f32_16x16x32_f16(Al[mi][1], Fh[ni][1], a, 0, 0, 0);
                acc[mi][ni] = a;
            }

        // per-col consts (ticn via L1; per-b row is 8 KB, hot)
        float tt[4], qq[4];
        #pragma unroll
        for (int ni = 0; ni < 4; ++ni) {
            tt[ni] = ticn[b * TT + t0 + ni * 16 + lr];
            qq[ni] = (-C2 * tt[ni]) * tt[ni];
        }

        // fused KL epilogue (base-2), scalar (round-6 codegen)
        #pragma unroll
        for (int mi = 0; mi < 2; ++mi)
            #pragma unroll
            for (int ni = 0; ni < 4; ++ni)
                #pragma unroll
                for (int r = 0; r < 4; ++r) {
                    float arg = fmaf(b_[mi][r], tt[ni], a_[mi][r]) + qq[ni];
                    float e   = fexp2(arg);
                    float x   = fmaf(acc[mi][ni][r], si_[mi][r], sip_[mi][r]);
                    float l2  = flog2(x);
                    SP[mi][r] += e;
                    KA[mi][r] = fmaf(e, arg - l2, KA[mi][r]);
                }
    }

    // --- reduce over 16 col-lanes per lg group, write partials ---
    #pragma unroll
    for (int mi = 0; mi < 2; ++mi)
        #pragma unroll
        for (int rr = 0; rr < 4; ++rr) {
            #pragma unroll
            for (int off = 1; off < 16; off <<= 1) {
                SP[mi][rr] += __shfl_xor(SP[mi][rr], off);
                KA[mi][rr] += __shfl_xor(KA[mi][rr], off);
            }
        }
    if (lr == 0) {
        #pragma unroll
        for (int mi = 0; mi < 2; ++mi)
            #pragma unroll
            for (int rr = 0; rr < 4; ++rr) {
                int p = p0 + w * 32 + mi * 16 + lg * 4 + rr;
                part[(size_t)chunk * (BB * TT) + b * TT + p] =
                    make_float2(SP[mi][rr], KA[mi][rr]);
            }
    }

    // --- last block combines partials and writes the scalar ---
    __threadfence();
    if (tid == 0) {
        int old = atomicAdd(cnt, 1);
        lastFlag = (old == NBLK - 1);
    }
    __syncthreads();
    if (!lastFlag) return;
    __threadfence();
    float tot = 0.f;
    for (int g = tid; g < BB * TT; g += 512) {
        float SPs = 0.f, KAs = 0.f;
        #pragma unroll
        for (int c = 0; c < NCHUNK; ++c) {
            float2 q = part[(size_t)c * (BB * TT) + g];
            SPs += q.x; KAs += q.y;
        }
        tot += LN2 * (KAs / SPs) - __logf(SPs);
    }
    #pragma unroll
    for (int off = 32; off; off >>= 1) tot += __shfl_xor(tot, off);
    if (l == 0) redf[w] = tot;
    __syncthreads();
    if (tid == 0) {
        float s = 0.f;
        #pragma unroll
        for (int i = 0; i < 8; ++i) s += redf[i];
        out[0] = s * (1.0f / 65536.0f);   // / (B * P)
    }
}

extern "C" void kernel_launch(void* const* d_in, const int* in_sizes, int n_in,
                              void* d_out, int out_size, void* d_ws, size_t ws_size,
                              hipStream_t stream) {
    const float* emb = (const float*)d_in[0];  // [B, T, D] fp32
    const float* tic = (const float*)d_in[1];  // [B, T] fp32
    float* out = (float*)d_out;
    char*  ws  = (char*)d_ws;

    float*          M    = (float*)(ws + OFF_M);
    int*            cnt  = (int*)(ws + OFF_CNT);
    float*          ticn = (float*)(ws + OFF_TICN);
    unsigned short* hi   = (unsigned short*)(ws + OFF_HI);
    unsigned short* lo   = (unsigned short*)(ws + OFF_LO);
    float2*         part = (float2*)(ws + OFF_PART);

    hipMemsetAsync(ws + OFF_M, 0, OFF_TICN, stream);   // zero M + counter

    k_prep<<<BB * 16 + BB, 256, 0, stream>>>(emb, tic, hi, lo, M, ticn);
    k_main<<<dim3((TT / 256) * NCHUNK, BB), 512, 0, stream>>>(hi, lo, ticn, M, part, cnt, out);
}

// Round 11
// 154.841 us; speedup vs baseline: 3.3544x; 2.5290x over previous
//
#include <hip/hip_runtime.h>
#include <hip/hip_bf16.h>
#include <math.h>

// Problem constants
#define BB 32
#define TT 2048
#define DD 64
#define NCHUNK 4
#define TCH (TT / NCHUNK)               // 512 targets per block
#define LOG2E 1.4426950408889634f
#define C2    0.7213475204444817f       // log2(e)/2
#define LN2   0.6931471805599453f

typedef __attribute__((ext_vector_type(8))) _Float16 h16x8;  // 8 f16 (4 VGPRs)
typedef __attribute__((ext_vector_type(4))) float    f32x4;  // MFMA C/D frag

// ws layout (bytes)
#define OFF_M    0u            // float[32*64]    = 8 KB
#define OFF_TICN 8192u         // float[65536]    = 256 KB
#define OFF_HI   270336u       // f16[32*2048*64] = 8 MB
#define OFF_LO   8658944u      // f16[...]        = 8 MB
#define OFF_PART 17047552u     // float2[4*65536] = 2 MB   (end ~19.1 MB)

__device__ __forceinline__ float h2f(unsigned short u) {
    _Float16 h; __builtin_memcpy(&h, &u, 2); return (float)h;
}
__device__ __forceinline__ unsigned short f2h(float f) {
    _Float16 h = (_Float16)f; unsigned short u; __builtin_memcpy(&u, &h, 2); return u;
}
__device__ __forceinline__ float fexp2(float x) {
    float r; asm("v_exp_f32 %0, %1" : "=v"(r) : "v"(x)); return r;
}
__device__ __forceinline__ float flog2(float x) {
    float r; asm("v_log_f32 %0, %1" : "=v"(r) : "v"(x)); return r;
}

// ---------- kernel 1: fused {L2-normalize -> f16 hi/lo + M sum} and tic-normalize ----------
// blocks [0, BB*16): embedding prep; blocks [BB*16, BB*16+BB): tic rows.
__global__ void k_prep(const float* __restrict__ emb, const float* __restrict__ tic,
                       unsigned short* __restrict__ hi, unsigned short* __restrict__ lo,
                       float* __restrict__ M, float* __restrict__ ticn) {
    if (blockIdx.x >= BB * 16) {
        int b = blockIdx.x - BB * 16;
        const float* row = tic + b * TT;
        float m = -1e30f;
        for (int t = threadIdx.x; t < TT; t += 256) m = fmaxf(m, row[t]);
        #pragma unroll
        for (int off = 32; off; off >>= 1) m = fmaxf(m, __shfl_xor(m, off));
        __shared__ float red[4];
        if ((threadIdx.x & 63) == 0) red[threadIdx.x >> 6] = m;
        __syncthreads();
        float mm = fmaxf(fmaxf(red[0], red[1]), fmaxf(red[2], red[3]));
        float inv = 1.0f / mm;
        for (int t = threadIdx.x; t < TT; t += 256) ticn[b * TT + t] = row[t] * inv;
        return;
    }
    const int b   = blockIdx.x >> 4;
    const int R0  = (blockIdx.x & 15) * 128;
    const int w   = threadIdx.x >> 6;
    const int l   = threadIdx.x & 63;
    const int sub = l >> 4;
    const int d4  = l & 15;

    float macc[4] = {0.f, 0.f, 0.f, 0.f};
    #pragma unroll
    for (int it = 0; it < 8; ++it) {
        int row = R0 + w * 32 + it * 4 + sub;
        size_t base = ((size_t)(b * TT + row)) * DD + d4 * 4;
        float4 v = *(const float4*)(emb + base);
        float ss = v.x * v.x + v.y * v.y + v.z * v.z + v.w * v.w;
        #pragma unroll
        for (int off = 1; off < 16; off <<= 1) ss += __shfl_xor(ss, off);
        float inv = 1.0f / fmaxf(sqrtf(ss), 1e-8f);
        float n0 = v.x * inv, n1 = v.y * inv, n2 = v.z * inv, n3 = v.w * inv;
        ushort4 hv, lv;
        hv.x = f2h(n0); lv.x = f2h(n0 - h2f(hv.x));
        hv.y = f2h(n1); lv.y = f2h(n1 - h2f(hv.y));
        hv.z = f2h(n2); lv.z = f2h(n2 - h2f(hv.z));
        hv.w = f2h(n3); lv.w = f2h(n3 - h2f(hv.w));
        *(ushort4*)(hi + base) = hv;
        *(ushort4*)(lo + base) = lv;
        macc[0] += n0; macc[1] += n1; macc[2] += n2; macc[3] += n3;
    }
    #pragma unroll
    for (int j = 0; j < 4; ++j) {
        macc[j] += __shfl_xor(macc[j], 16);
        macc[j] += __shfl_xor(macc[j], 32);
    }
    if (l < 16) {
        #pragma unroll
        for (int j = 0; j < 4; ++j)
            atomicAdd(&M[b * DD + d4 * 4 + j], macc[j]);
    }
}

// ---------- kernel 2: MFMA GEMM + fused KL epilogue — round-6 hot loop, no tail ----------
// grid ((TT/256)*NCHUNK = 32, BB = 32), 512 thr = 8 waves; wave owns 32 p-rows.
__launch_bounds__(512, 4)
__global__ void k_main(const unsigned short* __restrict__ hi,
                       const unsigned short* __restrict__ lo,
                       const float* __restrict__ ticn,
                       const float* __restrict__ M,
                       float2* __restrict__ part) {
    __shared__ unsigned short Bh[64 * 64];   // 8 KB, swizzled [t][d]
    __shared__ float ticrow[TT];             // 8 KB (pre-normalized, plain copy)

    const int b     = blockIdx.y;
    const int px    = blockIdx.x >> 2;
    const int chunk = blockIdx.x & 3;
    const int p0    = px * 256;
    const int tbase = chunk * TCH;
    const int tid   = threadIdx.x;
    const int w     = tid >> 6;
    const int l     = tid & 63;
    const int lr    = l & 15;
    const int lg    = l >> 4;

    // --- copy pre-normalized tic row into LDS (coalesced, no reduction) ---
    for (int t = tid; t < TT; t += 512) ticrow[t] = ticn[b * TT + t];

    // --- persistent A fragments: rows p0 + w*32 + mi*16 + lr, k = ks*32 + lg*8 ---
    h16x8 Ah[2][2], Al[2][2];
    #pragma unroll
    for (int mi = 0; mi < 2; ++mi)
        #pragma unroll
        for (int ks = 0; ks < 2; ++ks) {
            size_t off = ((size_t)(b * TT + p0 + w * 32 + mi * 16 + lr)) * DD + ks * 32 + lg * 8;
            Ah[mi][ks] = *(const h16x8*)(hi + off);
            Al[mi][ks] = *(const h16x8*)(lo + off);
        }

    // --- sinv: dot(ne_p, M) from A-frags (M direct from global, L2-hot) ---
    const float* Mb = M + b * DD;
    float mv[16];
    *(float4*)&mv[0]  = *(const float4*)(Mb + lg * 8);
    *(float4*)&mv[4]  = *(const float4*)(Mb + lg * 8 + 4);
    *(float4*)&mv[8]  = *(const float4*)(Mb + 32 + lg * 8);
    *(float4*)&mv[12] = *(const float4*)(Mb + 32 + lg * 8 + 4);
    float dotv[2];
    #pragma unroll
    for (int mi = 0; mi < 2; ++mi) {
        float s = 0.f;
        #pragma unroll
        for (int ks = 0; ks < 2; ++ks)
            #pragma unroll
            for (int e = 0; e < 8; ++e) {
                float av = (float)Ah[mi][ks][e] + (float)Al[mi][ks][e];
                s = fmaf(av, mv[ks * 8 + e], s);
            }
        s += __shfl_xor(s, 16);
        s += __shfl_xor(s, 32);
        dotv[mi] = s;   // full dot for row mi*16 + lr
    }

    __syncthreads();   // ticrow visible

    // --- per-row constants (C rows mi*16 + lg*4 + rr) ---
    float a_[2][4], b_[2][4], si_[2][4], sip_[2][4], SP[2][4], KA[2][4];
    #pragma unroll
    for (int mi = 0; mi < 2; ++mi)
        #pragma unroll
        for (int rr = 0; rr < 4; ++rr) {
            float dv = __shfl(dotv[mi], lg * 4 + rr);
            float si = 1.0f / (dv + (float)TT);
            si_[mi][rr]  = si;
            sip_[mi][rr] = si + 1e-6f;
            float tp = ticrow[p0 + w * 32 + mi * 16 + lg * 4 + rr];
            a_[mi][rr] = -C2 * tp * tp;
            b_[mi][rr] = LOG2E * tp;
            SP[mi][rr] = 0.f; KA[mi][rr] = 0.f;
        }

    // --- t-loop (round-6 structure, verbatim) ---
    for (int tile = 0; tile < TCH / 64; ++tile) {
        const int t0 = tbase + tile * 64;
        __syncthreads();
        {   // stage B-tile (64 t x 64 d, hi only), XOR-swizzled 16B chunks
            int r  = tid >> 3;
            int kc = tid & 7;
            size_t g = ((size_t)(b * TT + t0 + r)) * DD + kc * 8;
            int dst = r * 64 + ((kc ^ (r & 7)) << 3);
            *(ushort4*)&Bh[dst] = *(const ushort4*)(hi + g);
            *(ushort4*)&Bh[dst + 4] = *(const ushort4*)(hi + g + 4);
        }
        __syncthreads();

        // B fragments
        h16x8 Fh[4][2];
        #pragma unroll
        for (int ni = 0; ni < 4; ++ni) {
            int rB = ni * 16 + lr;
            #pragma unroll
            for (int ks = 0; ks < 2; ++ks) {
                int kc  = ks * 4 + lg;
                int off = rB * 64 + ((kc ^ (rB & 7)) << 3);
                Fh[ni][ks] = *(const h16x8*)&Bh[off];
            }
        }

        // MFMA: acc = hi_a.hi_b + lo_a.hi_b
        f32x4 acc[2][4];
        #pragma unroll
        for (int mi = 0; mi < 2; ++mi)
            #pragma unroll
            for (int ni = 0; ni < 4; ++ni) {
                f32x4 a = {0.f, 0.f, 0.f, 0.f};
                a = __builtin_amdgcn_mfma_f32_16x16x32_f16(Ah[mi][0], Fh[ni][0], a, 0, 0, 0);
                a = __builtin_amdgcn_mfma_f32_16x16x32_f16(Ah[mi][1], Fh[ni][1], a, 0, 0, 0);
                a = __builtin_amdgcn_mfma_f32_16x16x32_f16(Al[mi][0], Fh[ni][0], a, 0, 0, 0);
                a = __builtin_amdgcn_mfma_f32_16x16x32_f16(Al[mi][1], Fh[ni][1], a, 0, 0, 0);
                acc[mi][ni] = a;
            }

        // per-col consts from LDS
        float tt[4], qq[4];
        #pragma unroll
        for (int ni = 0; ni < 4; ++ni) {
            tt[ni] = ticrow[t0 + ni * 16 + lr];
            qq[ni] = (-C2 * tt[ni]) * tt[ni];
        }

        // fused KL epilogue (base-2), scalar (round-6 codegen)
        #pragma unroll
        for (int mi = 0; mi < 2; ++mi)
            #pragma unroll
            for (int ni = 0; ni < 4; ++ni)
                #pragma unroll
                for (int r = 0; r < 4; ++r) {
                    float arg = fmaf(b_[mi][r], tt[ni], a_[mi][r]) + qq[ni];
                    float e   = fexp2(arg);
                    float x   = fmaf(acc[mi][ni][r], si_[mi][r], sip_[mi][r]);
                    float l2  = flog2(x);
                    SP[mi][r] += e;
                    KA[mi][r] = fmaf(e, arg - l2, KA[mi][r]);
                }
    }

    // --- reduce over 16 col-lanes per lg group, write partials ---
    #pragma unroll
    for (int mi = 0; mi < 2; ++mi)
        #pragma unroll
        for (int rr = 0; rr < 4; ++rr) {
            #pragma unroll
            for (int off = 1; off < 16; off <<= 1) {
                SP[mi][rr] += __shfl_xor(SP[mi][rr], off);
                KA[mi][rr] += __shfl_xor(KA[mi][rr], off);
            }
        }
    if (lr == 0) {
        #pragma unroll
        for (int mi = 0; mi < 2; ++mi)
            #pragma unroll
            for (int rr = 0; rr < 4; ++rr) {
                int p = p0 + w * 32 + mi * 16 + lg * 4 + rr;
                part[(size_t)chunk * (BB * TT) + b * TT + p] =
                    make_float2(SP[mi][rr], KA[mi][rr]);
            }
    }
}

// ---------- kernel 3: combine partials, nonlinear reduce (round-6 proven) ----------
__global__ void k_fin(const float2* __restrict__ part, float* __restrict__ out) {
    int g = blockIdx.x * 256 + threadIdx.x;   // b*TT + p
    float SP = 0.f, KA2 = 0.f;
    #pragma unroll
    for (int c = 0; c < NCHUNK; ++c) {
        float2 q = part[(size_t)c * (BB * TT) + g];
        SP += q.x; KA2 += q.y;
    }
    float R = LN2 * (KA2 / SP) - __logf(SP);
    #pragma unroll
    for (int off = 32; off; off >>= 1) R += __shfl_xor(R, off);
    __shared__ float rb[4];
    if ((threadIdx.x & 63) == 0) rb[threadIdx.x >> 6] = R;
    __syncthreads();
    if (threadIdx.x == 0)
        atomicAdd(out, (rb[0] + rb[1] + rb[2] + rb[3]) * (1.0f / 65536.0f));
}

extern "C" void kernel_launch(void* const* d_in, const int* in_sizes, int n_in,
                              void* d_out, int out_size, void* d_ws, size_t ws_size,
                              hipStream_t stream) {
    const float* emb = (const float*)d_in[0];  // [B, T, D] fp32
    const float* tic = (const float*)d_in[1];  // [B, T] fp32
    float* out = (float*)d_out;
    char*  ws  = (char*)d_ws;

    float*          M    = (float*)(ws + OFF_M);
    float*          ticn = (float*)(ws + OFF_TICN);
    unsigned short* hi   = (unsigned short*)(ws + OFF_HI);
    unsigned short* lo   = (unsigned short*)(ws + OFF_LO);
    float2*         part = (float2*)(ws + OFF_PART);

    hipMemsetAsync(out, 0, sizeof(float), stream);
    hipMemsetAsync(M, 0, BB * DD * sizeof(float), stream);

    k_prep<<<BB * 16 + BB, 256, 0, stream>>>(emb, tic, hi, lo, M, ticn);
    k_main<<<dim3((TT / 256) * NCHUNK, BB), 512, 0, stream>>>(hi, lo, ticn, M, part);
    k_fin <<<(BB * TT) / 256, 256, 0, stream>>>(part, out);
}

// Round 12
// 142.101 us; speedup vs baseline: 3.6551x; 1.0897x over previous
//
#include <hip/hip_runtime.h>
#include <hip/hip_bf16.h>
#include <math.h>

// Problem constants
#define BB 32
#define TT 2048
#define DD 64
#define NCHUNK 4
#define TCH (TT / NCHUNK)               // 512 targets per block
#define LOG2E 1.4426950408889634f
#define C2    0.7213475204444817f       // log2(e)/2
#define LN2   0.6931471805599453f

typedef __attribute__((ext_vector_type(8))) _Float16 h16x8;  // 8 f16 (4 VGPRs)
typedef __attribute__((ext_vector_type(4))) float    f32x4;  // MFMA C/D frag

// ws layout (bytes)
#define OFF_MP   0u            // float[32*16*64] partials = 128 KB
#define OFF_TICN 131072u       // float[65536]    = 256 KB
#define OFF_HI   393216u       // f16[32*2048*64] = 8 MB
#define OFF_LO   8781824u      // f16[...]        = 8 MB
#define OFF_PART 17170432u     // float2[4*65536] = 2 MB   (end ~19.2 MB)

__device__ __forceinline__ float h2f(unsigned short u) {
    _Float16 h; __builtin_memcpy(&h, &u, 2); return (float)h;
}
__device__ __forceinline__ unsigned short f2h(float f) {
    _Float16 h = (_Float16)f; unsigned short u; __builtin_memcpy(&u, &h, 2); return u;
}
__device__ __forceinline__ float fexp2(float x) {
    float r; asm("v_exp_f32 %0, %1" : "=v"(r) : "v"(x)); return r;
}
__device__ __forceinline__ float flog2(float x) {
    float r; asm("v_log_f32 %0, %1" : "=v"(r) : "v"(x)); return r;
}

// ---------- kernel 1: fused {L2-normalize -> f16 hi/lo + M partial} and tic-normalize ----------
// blocks [0, BB*16): embedding prep (b = blk>>4, j = blk&15); blocks [BB*16, BB*16+BB): tic rows.
// No atomics: per-block M partial -> Mpart[b*16+j][64].
__global__ void k_prep(const float* __restrict__ emb, const float* __restrict__ tic,
                       unsigned short* __restrict__ hi, unsigned short* __restrict__ lo,
                       float* __restrict__ Mpart, float* __restrict__ ticn) {
    if (blockIdx.x >= BB * 16) {
        int b = blockIdx.x - BB * 16;
        const float* row = tic + b * TT;
        float m = -1e30f;
        for (int t = threadIdx.x; t < TT; t += 256) m = fmaxf(m, row[t]);
        #pragma unroll
        for (int off = 32; off; off >>= 1) m = fmaxf(m, __shfl_xor(m, off));
        __shared__ float red[4];
        if ((threadIdx.x & 63) == 0) red[threadIdx.x >> 6] = m;
        __syncthreads();
        float mm = fmaxf(fmaxf(red[0], red[1]), fmaxf(red[2], red[3]));
        float inv = 1.0f / mm;
        for (int t = threadIdx.x; t < TT; t += 256) ticn[b * TT + t] = row[t] * inv;
        return;
    }
    const int b   = blockIdx.x >> 4;
    const int j16 = blockIdx.x & 15;
    const int R0  = j16 * 128;
    const int w   = threadIdx.x >> 6;
    const int l   = threadIdx.x & 63;
    const int sub = l >> 4;
    const int d4  = l & 15;

    float macc[4] = {0.f, 0.f, 0.f, 0.f};
    #pragma unroll
    for (int it = 0; it < 8; ++it) {
        int row = R0 + w * 32 + it * 4 + sub;
        size_t base = ((size_t)(b * TT + row)) * DD + d4 * 4;
        float4 v = *(const float4*)(emb + base);
        float ss = v.x * v.x + v.y * v.y + v.z * v.z + v.w * v.w;
        #pragma unroll
        for (int off = 1; off < 16; off <<= 1) ss += __shfl_xor(ss, off);
        float inv = 1.0f / fmaxf(sqrtf(ss), 1e-8f);
        float n0 = v.x * inv, n1 = v.y * inv, n2 = v.z * inv, n3 = v.w * inv;
        ushort4 hv, lv;
        hv.x = f2h(n0); lv.x = f2h(n0 - h2f(hv.x));
        hv.y = f2h(n1); lv.y = f2h(n1 - h2f(hv.y));
        hv.z = f2h(n2); lv.z = f2h(n2 - h2f(hv.z));
        hv.w = f2h(n3); lv.w = f2h(n3 - h2f(hv.w));
        *(ushort4*)(hi + base) = hv;
        *(ushort4*)(lo + base) = lv;
        macc[0] += n0; macc[1] += n1; macc[2] += n2; macc[3] += n3;
    }
    #pragma unroll
    for (int jj = 0; jj < 4; ++jj) {
        macc[jj] += __shfl_xor(macc[jj], 16);
        macc[jj] += __shfl_xor(macc[jj], 32);
    }
    // cross-wave LDS reduce -> one non-atomic write per d
    __shared__ float redM[4][64];
    if (l < 16) {
        #pragma unroll
        for (int jj = 0; jj < 4; ++jj) redM[w][d4 * 4 + jj] = macc[jj];
    }
    __syncthreads();
    if (threadIdx.x < 64) {
        float s = redM[0][threadIdx.x] + redM[1][threadIdx.x] +
                  redM[2][threadIdx.x] + redM[3][threadIdx.x];
        Mpart[(size_t)(b * 16 + j16) * 64 + threadIdx.x] = s;
    }
}

// ---------- kernel 2: MFMA GEMM + fused KL epilogue — round-11 hot loop ----------
// grid ((TT/256)*NCHUNK = 32, BB = 32), 512 thr = 8 waves; wave owns 32 p-rows.
__launch_bounds__(512, 4)
__global__ void k_main(const unsigned short* __restrict__ hi,
                       const unsigned short* __restrict__ lo,
                       const float* __restrict__ ticn,
                       const float* __restrict__ Mpart,
                       float2* __restrict__ part,
                       float* __restrict__ out) {
    __shared__ unsigned short Bh[64 * 64];   // 8 KB, swizzled [t][d]
    __shared__ float ticch[TCH];             // 2 KB: this chunk's t-values
    __shared__ float Msh[DD];

    const int b     = blockIdx.y;
    const int px    = blockIdx.x >> 2;
    const int chunk = blockIdx.x & 3;
    const int p0    = px * 256;
    const int tbase = chunk * TCH;
    const int tid   = threadIdx.x;
    const int w     = tid >> 6;
    const int l     = tid & 63;
    const int lr    = l & 15;
    const int lg    = l >> 4;

    // zero the output once; k_fin (separate node) only starts after all k_main blocks end
    if (blockIdx.x == 0 && blockIdx.y == 0 && tid == 0) out[0] = 0.f;

    // --- copy this chunk's tic values into LDS; sum M partials into Msh ---
    if (tid < TCH) ticch[tid] = ticn[b * TT + tbase + tid];
    if (tid >= 512 - DD) {
        int d = tid - (512 - DD);
        float s = 0.f;
        #pragma unroll
        for (int j = 0; j < 16; ++j) s += Mpart[(size_t)(b * 16 + j) * 64 + d];
        Msh[d] = s;
    }

    // --- persistent A fragments: rows p0 + w*32 + mi*16 + lr, k = ks*32 + lg*8 ---
    h16x8 Ah[2][2], Al[2][2];
    #pragma unroll
    for (int mi = 0; mi < 2; ++mi)
        #pragma unroll
        for (int ks = 0; ks < 2; ++ks) {
            size_t off = ((size_t)(b * TT + p0 + w * 32 + mi * 16 + lr)) * DD + ks * 32 + lg * 8;
            Ah[mi][ks] = *(const h16x8*)(hi + off);
            Al[mi][ks] = *(const h16x8*)(lo + off);
        }

    __syncthreads();   // ticch + Msh visible

    // --- sinv: dot(ne_p, M) from A-frags ---
    float mv[16];
    *(float4*)&mv[0]  = *(const float4*)&Msh[lg * 8];
    *(float4*)&mv[4]  = *(const float4*)&Msh[lg * 8 + 4];
    *(float4*)&mv[8]  = *(const float4*)&Msh[32 + lg * 8];
    *(float4*)&mv[12] = *(const float4*)&Msh[32 + lg * 8 + 4];
    float dotv[2], tpl[2];
    #pragma unroll
    for (int mi = 0; mi < 2; ++mi) {
        float s = 0.f;
        #pragma unroll
        for (int ks = 0; ks < 2; ++ks)
            #pragma unroll
            for (int e = 0; e < 8; ++e) {
                float av = (float)Ah[mi][ks][e] + (float)Al[mi][ks][e];
                s = fmaf(av, mv[ks * 8 + e], s);
            }
        s += __shfl_xor(s, 16);
        s += __shfl_xor(s, 32);
        dotv[mi] = s;                                   // dot of row mi*16+lr
        tpl[mi]  = ticn[b * TT + p0 + w * 32 + mi * 16 + lr];
    }

    // --- per-row constants (C rows mi*16 + lg*4 + rr) ---
    float a_[2][4], b_[2][4], si_[2][4], sip_[2][4], SP[2][4], KA[2][4];
    #pragma unroll
    for (int mi = 0; mi < 2; ++mi)
        #pragma unroll
        for (int rr = 0; rr < 4; ++rr) {
            float dv = __shfl(dotv[mi], lg * 4 + rr);
            float tp = __shfl(tpl[mi],  lg * 4 + rr);
            float si = 1.0f / (dv + (float)TT);
            si_[mi][rr]  = si;
            sip_[mi][rr] = si + 1e-6f;
            a_[mi][rr] = -C2 * tp * tp;
            b_[mi][rr] = LOG2E * tp;
            SP[mi][rr] = 0.f; KA[mi][rr] = 0.f;
        }

    // --- t-loop (round-6/11 structure, verbatim) ---
    for (int tile = 0; tile < TCH / 64; ++tile) {
        const int t0 = tbase + tile * 64;
        __syncthreads();
        {   // stage B-tile (64 t x 64 d, hi only), XOR-swizzled 16B chunks
            int r  = tid >> 3;
            int kc = tid & 7;
            size_t g = ((size_t)(b * TT + t0 + r)) * DD + kc * 8;
            int dst = r * 64 + ((kc ^ (r & 7)) << 3);
            *(ushort4*)&Bh[dst] = *(const ushort4*)(hi + g);
            *(ushort4*)&Bh[dst + 4] = *(const ushort4*)(hi + g + 4);
        }
        __syncthreads();

        // B fragments
        h16x8 Fh[4][2];
        #pragma unroll
        for (int ni = 0; ni < 4; ++ni) {
            int rB = ni * 16 + lr;
            #pragma unroll
            for (int ks = 0; ks < 2; ++ks) {
                int kc  = ks * 4 + lg;
                int off = rB * 64 + ((kc ^ (rB & 7)) << 3);
                Fh[ni][ks] = *(const h16x8*)&Bh[off];
            }
        }

        // MFMA: acc = hi_a.hi_b + lo_a.hi_b
        f32x4 acc[2][4];
        #pragma unroll
        for (int mi = 0; mi < 2; ++mi)
            #pragma unroll
            for (int ni = 0; ni < 4; ++ni) {
                f32x4 a = {0.f, 0.f, 0.f, 0.f};
                a = __builtin_amdgcn_mfma_f32_16x16x32_f16(Ah[mi][0], Fh[ni][0], a, 0, 0, 0);
                a = __builtin_amdgcn_mfma_f32_16x16x32_f16(Ah[mi][1], Fh[ni][1], a, 0, 0, 0);
                a = __builtin_amdgcn_mfma_f32_16x16x32_f16(Al[mi][0], Fh[ni][0], a, 0, 0, 0);
                a = __builtin_amdgcn_mfma_f32_16x16x32_f16(Al[mi][1], Fh[ni][1], a, 0, 0, 0);
                acc[mi][ni] = a;
            }

        // per-col consts from LDS (chunk-local indexing)
        float tt[4], qq[4];
        #pragma unroll
        for (int ni = 0; ni < 4; ++ni) {
            tt[ni] = ticch[tile * 64 + ni * 16 + lr];
            qq[ni] = (-C2 * tt[ni]) * tt[ni];
        }

        // fused KL epilogue (base-2), scalar (round-11 codegen)
        #pragma unroll
        for (int mi = 0; mi < 2; ++mi)
            #pragma unroll
            for (int ni = 0; ni < 4; ++ni)
                #pragma unroll
                for (int r = 0; r < 4; ++r) {
                    float arg = fmaf(b_[mi][r], tt[ni], a_[mi][r]) + qq[ni];
                    float e   = fexp2(arg);
                    float x   = fmaf(acc[mi][ni][r], si_[mi][r], sip_[mi][r]);
                    float l2  = flog2(x);
                    SP[mi][r] += e;
                    KA[mi][r] = fmaf(e, arg - l2, KA[mi][r]);
                }
    }

    // --- reduce over 16 col-lanes per lg group, write partials ---
    #pragma unroll
    for (int mi = 0; mi < 2; ++mi)
        #pragma unroll
        for (int rr = 0; rr < 4; ++rr) {
            #pragma unroll
            for (int off = 1; off < 16; off <<= 1) {
                SP[mi][rr] += __shfl_xor(SP[mi][rr], off);
                KA[mi][rr] += __shfl_xor(KA[mi][rr], off);
            }
        }
    if (lr == 0) {
        #pragma unroll
        for (int mi = 0; mi < 2; ++mi)
            #pragma unroll
            for (int rr = 0; rr < 4; ++rr) {
                int p = p0 + w * 32 + mi * 16 + lg * 4 + rr;
                part[(size_t)chunk * (BB * TT) + b * TT + p] =
                    make_float2(SP[mi][rr], KA[mi][rr]);
            }
    }
}

// ---------- kernel 3: combine partials, nonlinear reduce (round-6 proven) ----------
__global__ void k_fin(const float2* __restrict__ part, float* __restrict__ out) {
    int g = blockIdx.x * 256 + threadIdx.x;   // b*TT + p
    float SP = 0.f, KA2 = 0.f;
    #pragma unroll
    for (int c = 0; c < NCHUNK; ++c) {
        float2 q = part[(size_t)c * (BB * TT) + g];
        SP += q.x; KA2 += q.y;
    }
    float R = LN2 * (KA2 / SP) - __logf(SP);
    #pragma unroll
    for (int off = 32; off; off >>= 1) R += __shfl_xor(R, off);
    __shared__ float rb[4];
    if ((threadIdx.x & 63) == 0) rb[threadIdx.x >> 6] = R;
    __syncthreads();
    if (threadIdx.x == 0)
        atomicAdd(out, (rb[0] + rb[1] + rb[2] + rb[3]) * (1.0f / 65536.0f));
}

extern "C" void kernel_launch(void* const* d_in, const int* in_sizes, int n_in,
                              void* d_out, int out_size, void* d_ws, size_t ws_size,
                              hipStream_t stream) {
    const float* emb = (const float*)d_in[0];  // [B, T, D] fp32
    const float* tic = (const float*)d_in[1];  // [B, T] fp32
    float* out = (float*)d_out;
    char*  ws  = (char*)d_ws;

    float*          Mpart = (float*)(ws + OFF_MP);
    float*          ticn  = (float*)(ws + OFF_TICN);
    unsigned short* hi    = (unsigned short*)(ws + OFF_HI);
    unsigned short* lo    = (unsigned short*)(ws + OFF_LO);
    float2*         part  = (float2*)(ws + OFF_PART);

    k_prep<<<BB * 16 + BB, 256, 0, stream>>>(emb, tic, hi, lo, Mpart, ticn);
    k_main<<<dim3((TT / 256) * NCHUNK, BB), 512, 0, stream>>>(hi, lo, ticn, Mpart, part, out);
    k_fin <<<(BB * TT) / 256, 256, 0, stream>>>(part, out);
}

// Round 13
// 138.286 us; speedup vs baseline: 3.7559x; 1.0276x over previous
//
#include <hip/hip_runtime.h>
#include <hip/hip_bf16.h>
#include <math.h>

// Problem constants
#define BB 32
#define TT 2048
#define DD 64
#define NCHUNK 4
#define TCH (TT / NCHUNK)               // 512 targets per block
#define LOG2E 1.4426950408889634f
#define C2    0.7213475204444817f       // log2(e)/2
#define LN2   0.6931471805599453f

typedef __attribute__((ext_vector_type(8))) _Float16 h16x8;  // 8 f16 (4 VGPRs)
typedef __attribute__((ext_vector_type(4))) float    f32x4;  // MFMA C/D frag

// ws layout (bytes)
#define OFF_MP   0u            // float[32*16*64] partials = 128 KB
#define OFF_TICN 131072u       // float[65536]    = 256 KB
#define OFF_HI   393216u       // f16[32*2048*64] = 8 MB
#define OFF_LO   8781824u      // f16[...]        = 8 MB
#define OFF_PART 17170432u     // float2[4*65536] = 2 MB   (end ~19.2 MB)

__device__ __forceinline__ float h2f(unsigned short u) {
    _Float16 h; __builtin_memcpy(&h, &u, 2); return (float)h;
}
__device__ __forceinline__ unsigned short f2h(float f) {
    _Float16 h = (_Float16)f; unsigned short u; __builtin_memcpy(&u, &h, 2); return u;
}
__device__ __forceinline__ float fexp2(float x) {
    float r; asm("v_exp_f32 %0, %1" : "=v"(r) : "v"(x)); return r;
}
__device__ __forceinline__ float flog2(float x) {
    float r; asm("v_log_f32 %0, %1" : "=v"(r) : "v"(x)); return r;
}

// ---------- kernel 1: fused {L2-normalize -> f16 hi/lo + M partial} and tic-normalize ----------
__global__ void k_prep(const float* __restrict__ emb, const float* __restrict__ tic,
                       unsigned short* __restrict__ hi, unsigned short* __restrict__ lo,
                       float* __restrict__ Mpart, float* __restrict__ ticn) {
    if (blockIdx.x >= BB * 16) {
        int b = blockIdx.x - BB * 16;
        const float* row = tic + b * TT;
        float m = -1e30f;
        for (int t = threadIdx.x; t < TT; t += 256) m = fmaxf(m, row[t]);
        #pragma unroll
        for (int off = 32; off; off >>= 1) m = fmaxf(m, __shfl_xor(m, off));
        __shared__ float red[4];
        if ((threadIdx.x & 63) == 0) red[threadIdx.x >> 6] = m;
        __syncthreads();
        float mm = fmaxf(fmaxf(red[0], red[1]), fmaxf(red[2], red[3]));
        float inv = 1.0f / mm;
        for (int t = threadIdx.x; t < TT; t += 256) ticn[b * TT + t] = row[t] * inv;
        return;
    }
    const int b   = blockIdx.x >> 4;
    const int j16 = blockIdx.x & 15;
    const int R0  = j16 * 128;
    const int w   = threadIdx.x >> 6;
    const int l   = threadIdx.x & 63;
    const int sub = l >> 4;
    const int d4  = l & 15;

    float macc[4] = {0.f, 0.f, 0.f, 0.f};
    #pragma unroll
    for (int it = 0; it < 8; ++it) {
        int row = R0 + w * 32 + it * 4 + sub;
        size_t base = ((size_t)(b * TT + row)) * DD + d4 * 4;
        float4 v = *(const float4*)(emb + base);
        float ss = v.x * v.x + v.y * v.y + v.z * v.z + v.w * v.w;
        #pragma unroll
        for (int off = 1; off < 16; off <<= 1) ss += __shfl_xor(ss, off);
        float inv = 1.0f / fmaxf(sqrtf(ss), 1e-8f);
        float n0 = v.x * inv, n1 = v.y * inv, n2 = v.z * inv, n3 = v.w * inv;
        ushort4 hv, lv;
        hv.x = f2h(n0); lv.x = f2h(n0 - h2f(hv.x));
        hv.y = f2h(n1); lv.y = f2h(n1 - h2f(hv.y));
        hv.z = f2h(n2); lv.z = f2h(n2 - h2f(hv.z));
        hv.w = f2h(n3); lv.w = f2h(n3 - h2f(hv.w));
        *(ushort4*)(hi + base) = hv;
        *(ushort4*)(lo + base) = lv;
        macc[0] += n0; macc[1] += n1; macc[2] += n2; macc[3] += n3;
    }
    #pragma unroll
    for (int jj = 0; jj < 4; ++jj) {
        macc[jj] += __shfl_xor(macc[jj], 16);
        macc[jj] += __shfl_xor(macc[jj], 32);
    }
    __shared__ float redM[4][64];
    if (l < 16) {
        #pragma unroll
        for (int jj = 0; jj < 4; ++jj) redM[w][d4 * 4 + jj] = macc[jj];
    }
    __syncthreads();
    if (threadIdx.x < 64) {
        float s = redM[0][threadIdx.x] + redM[1][threadIdx.x] +
                  redM[2][threadIdx.x] + redM[3][threadIdx.x];
        Mpart[(size_t)(b * 16 + j16) * 64 + threadIdx.x] = s;
    }
}

// ---------- kernel 2: MFMA GEMM + fused KL epilogue — T14 async-STAGE t-loop ----------
// grid ((TT/256)*NCHUNK = 32, BB = 32), 512 thr = 8 waves; wave owns 32 p-rows.
__launch_bounds__(512, 4)
__global__ void k_main(const unsigned short* __restrict__ hi,
                       const unsigned short* __restrict__ lo,
                       const float* __restrict__ ticn,
                       const float* __restrict__ Mpart,
                       float2* __restrict__ part,
                       float* __restrict__ out) {
    __shared__ unsigned short Bh[64 * 64];   // 8 KB, swizzled [t][d]
    __shared__ float ticch[TCH];             // 2 KB: this chunk's t-values
    __shared__ float Msh[DD];

    const int b     = blockIdx.y;
    const int px    = blockIdx.x >> 2;
    const int chunk = blockIdx.x & 3;
    const int p0    = px * 256;
    const int tbase = chunk * TCH;
    const int tid   = threadIdx.x;
    const int w     = tid >> 6;
    const int l     = tid & 63;
    const int lr    = l & 15;
    const int lg    = l >> 4;

    // zero the output once; k_fin (separate node) only starts after all k_main blocks end
    if (blockIdx.x == 0 && blockIdx.y == 0 && tid == 0) out[0] = 0.f;

    // --- copy this chunk's tic values into LDS; sum M partials into Msh ---
    if (tid < TCH) ticch[tid] = ticn[b * TT + tbase + tid];
    if (tid >= 512 - DD) {
        int d = tid - (512 - DD);
        float s = 0.f;
        #pragma unroll
        for (int j = 0; j < 16; ++j) s += Mpart[(size_t)(b * 16 + j) * 64 + d];
        Msh[d] = s;
    }

    // --- persistent A fragments: rows p0 + w*32 + mi*16 + lr, k = ks*32 + lg*8 ---
    h16x8 Ah[2][2], Al[2][2];
    #pragma unroll
    for (int mi = 0; mi < 2; ++mi)
        #pragma unroll
        for (int ks = 0; ks < 2; ++ks) {
            size_t off = ((size_t)(b * TT + p0 + w * 32 + mi * 16 + lr)) * DD + ks * 32 + lg * 8;
            Ah[mi][ks] = *(const h16x8*)(hi + off);
            Al[mi][ks] = *(const h16x8*)(lo + off);
        }

    // --- T14 staging setup: this thread stages 16B of row r, chunk kc, each tile ---
    const int  sr  = tid >> 3;               // 0..63 t-row within tile
    const int  skc = tid & 7;                // 16B chunk within row
    const int  sdst = sr * 64 + ((skc ^ (sr & 7)) << 3);
    const unsigned short* sgp = hi + ((size_t)(b * TT + tbase + sr)) * DD + skc * 8;
    ushort4 s0 = *(const ushort4*)(sgp);     // prologue: tile 0 staged in regs
    ushort4 s1 = *(const ushort4*)(sgp + 4);

    __syncthreads();   // ticch + Msh visible

    // --- sinv: dot(ne_p, M) from A-frags ---
    float mv[16];
    *(float4*)&mv[0]  = *(const float4*)&Msh[lg * 8];
    *(float4*)&mv[4]  = *(const float4*)&Msh[lg * 8 + 4];
    *(float4*)&mv[8]  = *(const float4*)&Msh[32 + lg * 8];
    *(float4*)&mv[12] = *(const float4*)&Msh[32 + lg * 8 + 4];
    float dotv[2], tpl[2];
    #pragma unroll
    for (int mi = 0; mi < 2; ++mi) {
        float s = 0.f;
        #pragma unroll
        for (int ks = 0; ks < 2; ++ks)
            #pragma unroll
            for (int e = 0; e < 8; ++e) {
                float av = (float)Ah[mi][ks][e] + (float)Al[mi][ks][e];
                s = fmaf(av, mv[ks * 8 + e], s);
            }
        s += __shfl_xor(s, 16);
        s += __shfl_xor(s, 32);
        dotv[mi] = s;                                   // dot of row mi*16+lr
        tpl[mi]  = ticn[b * TT + p0 + w * 32 + mi * 16 + lr];
    }

    // --- per-row constants (C rows mi*16 + lg*4 + rr) ---
    float a_[2][4], b_[2][4], si_[2][4], sip_[2][4], SP[2][4], KA[2][4];
    #pragma unroll
    for (int mi = 0; mi < 2; ++mi)
        #pragma unroll
        for (int rr = 0; rr < 4; ++rr) {
            float dv = __shfl(dotv[mi], lg * 4 + rr);
            float tp = __shfl(tpl[mi],  lg * 4 + rr);
            float si = 1.0f / (dv + (float)TT);
            si_[mi][rr]  = si;
            sip_[mi][rr] = si + 1e-6f;
            a_[mi][rr] = -C2 * tp * tp;
            b_[mi][rr] = LOG2E * tp;
            SP[mi][rr] = 0.f; KA[mi][rr] = 0.f;
        }

    // --- t-loop: write staged regs, barrier, issue NEXT loads, compute, barrier ---
    for (int tile = 0; tile < TCH / 64; ++tile) {
        // write previously-loaded tile into LDS
        *(ushort4*)&Bh[sdst]     = s0;
        *(ushort4*)&Bh[sdst + 4] = s1;
        __syncthreads();          // Bh ready

        // issue next tile's global loads now — latency hides under MFMA+epilogue
        if (tile + 1 < TCH / 64) {
            const unsigned short* gp = sgp + (size_t)(tile + 1) * 64 * DD;
            s0 = *(const ushort4*)(gp);
            s1 = *(const ushort4*)(gp + 4);
        }

        // B fragments
        h16x8 Fh[4][2];
        #pragma unroll
        for (int ni = 0; ni < 4; ++ni) {
            int rB = ni * 16 + lr;
            #pragma unroll
            for (int ks = 0; ks < 2; ++ks) {
                int kc  = ks * 4 + lg;
                int off = rB * 64 + ((kc ^ (rB & 7)) << 3);
                Fh[ni][ks] = *(const h16x8*)&Bh[off];
            }
        }

        // MFMA: acc = hi_a.hi_b + lo_a.hi_b
        f32x4 acc[2][4];
        #pragma unroll
        for (int mi = 0; mi < 2; ++mi)
            #pragma unroll
            for (int ni = 0; ni < 4; ++ni) {
                f32x4 a = {0.f, 0.f, 0.f, 0.f};
                a = __builtin_amdgcn_mfma_f32_16x16x32_f16(Ah[mi][0], Fh[ni][0], a, 0, 0, 0);
                a = __builtin_amdgcn_mfma_f32_16x16x32_f16(Ah[mi][1], Fh[ni][1], a, 0, 0, 0);
                a = __builtin_amdgcn_mfma_f32_16x16x32_f16(Al[mi][0], Fh[ni][0], a, 0, 0, 0);
                a = __builtin_amdgcn_mfma_f32_16x16x32_f16(Al[mi][1], Fh[ni][1], a, 0, 0, 0);
                acc[mi][ni] = a;
            }

        // per-col consts from LDS (chunk-local indexing)
        float tt[4], qq[4];
        #pragma unroll
        for (int ni = 0; ni < 4; ++ni) {
            tt[ni] = ticch[tile * 64 + ni * 16 + lr];
            qq[ni] = (-C2 * tt[ni]) * tt[ni];
        }

        // fused KL epilogue (base-2), scalar
        #pragma unroll
        for (int mi = 0; mi < 2; ++mi)
            #pragma unroll
            for (int ni = 0; ni < 4; ++ni)
                #pragma unroll
                for (int r = 0; r < 4; ++r) {
                    float arg = fmaf(b_[mi][r], tt[ni], a_[mi][r]) + qq[ni];
                    float e   = fexp2(arg);
                    float x   = fmaf(acc[mi][ni][r], si_[mi][r], sip_[mi][r]);
                    float l2  = flog2(x);
                    SP[mi][r] += e;
                    KA[mi][r] = fmaf(e, arg - l2, KA[mi][r]);
                }

        __syncthreads();   // all Bh reads done; next iter overwrites
    }

    // --- reduce over 16 col-lanes per lg group, write partials ---
    #pragma unroll
    for (int mi = 0; mi < 2; ++mi)
        #pragma unroll
        for (int rr = 0; rr < 4; ++rr) {
            #pragma unroll
            for (int off = 1; off < 16; off <<= 1) {
                SP[mi][rr] += __shfl_xor(SP[mi][rr], off);
                KA[mi][rr] += __shfl_xor(KA[mi][rr], off);
            }
        }
    if (lr == 0) {
        #pragma unroll
        for (int mi = 0; mi < 2; ++mi)
            #pragma unroll
            for (int rr = 0; rr < 4; ++rr) {
                int p = p0 + w * 32 + mi * 16 + lg * 4 + rr;
                part[(size_t)chunk * (BB * TT) + b * TT + p] =
                    make_float2(SP[mi][rr], KA[mi][rr]);
            }
    }
}

// ---------- kernel 3: combine partials, nonlinear reduce ----------
__global__ void k_fin(const float2* __restrict__ part, float* __restrict__ out) {
    int g = blockIdx.x * 256 + threadIdx.x;   // b*TT + p
    float SP = 0.f, KA2 = 0.f;
    #pragma unroll
    for (int c = 0; c < NCHUNK; ++c) {
        float2 q = part[(size_t)c * (BB * TT) + g];
        SP += q.x; KA2 += q.y;
    }
    float R = LN2 * (KA2 / SP) - __logf(SP);
    #pragma unroll
    for (int off = 32; off; off >>= 1) R += __shfl_xor(R, off);
    __shared__ float rb[4];
    if ((threadIdx.x & 63) == 0) rb[threadIdx.x >> 6] = R;
    __syncthreads();
    if (threadIdx.x == 0)
        atomicAdd(out, (rb[0] + rb[1] + rb[2] + rb[3]) * (1.0f / 65536.0f));
}

extern "C" void kernel_launch(void* const* d_in, const int* in_sizes, int n_in,
                              void* d_out, int out_size, void* d_ws, size_t ws_size,
                              hipStream_t stream) {
    const float* emb = (const float*)d_in[0];  // [B, T, D] fp32
    const float* tic = (const float*)d_in[1];  // [B, T] fp32
    float* out = (float*)d_out;
    char*  ws  = (char*)d_ws;

    float*          Mpart = (float*)(ws + OFF_MP);
    float*          ticn  = (float*)(ws + OFF_TICN);
    unsigned short* hi    = (unsigned short*)(ws + OFF_HI);
    unsigned short* lo    = (unsigned short*)(ws + OFF_LO);
    float2*         part  = (float2*)(ws + OFF_PART);

    k_prep<<<BB * 16 + BB, 256, 0, stream>>>(emb, tic, hi, lo, Mpart, ticn);
    k_main<<<dim3((TT / 256) * NCHUNK, BB), 512, 0, stream>>>(hi, lo, ticn, Mpart, part, out);
    k_fin <<<(BB * TT) / 256, 256, 0, stream>>>(part, out);
}